// Round 6
// baseline (899.387 us; speedup 1.0000x reference)
//
#include <hip/hip_runtime.h>

#define N_USERS 100000
#define N_ITEMS 50000
#define DIM     64
#define N_NODES (N_USERS + N_ITEMS + 1)   /* 150001 */
#define N_EDGES 4800000

static constexpr long long NF = (long long)N_NODES * DIM;   // 9,600,064 floats per tensor

// ------------------- coarse-bucket counting-sort geometry -------------------
#define NCB      256                       /* coarse buckets                  */
#define CB_ROWS  586                       /* rows per bucket: 586*256=150016 */
#define CHUNK_E  8192                      /* edges per chunk                 */
#define BINA_T   256
#define NCHUNK   ((N_EDGES + CHUNK_E - 1) / CHUNK_E)   /* 586 */
#define PB_T     1024

// ---------------------------------------------------------------------------
// ego = concat(user_emb, item_emb)  (float4-vectorized)
// ---------------------------------------------------------------------------
__global__ void concat_kernel(const float4* __restrict__ user,
                              const float4* __restrict__ item,
                              float4* __restrict__ ego) {
    int i = blockIdx.x * blockDim.x + threadIdx.x;
    const int userF4 = N_USERS * DIM / 4;
    const int totF4  = (int)(NF / 4);
    if (i < userF4)      ego[i] = user[i];
    else if (i < totF4)  ego[i] = item[i - userF4];
}

// ---------------------------------------------------------------------------
// build 1: per-chunk bucket histogram -> cnt[chunk][bucket]. No atomics
// beyond LDS. (Replaces atomic range reservation: the old bcur device-scope
// atomics serialized ~586 same-line RMWs per counter on every wg's critical
// path.)
// ---------------------------------------------------------------------------
__global__ void __launch_bounds__(BINA_T)
binA_count_kernel(const int* __restrict__ rows, int* __restrict__ cnt) {
    __shared__ int hist[NCB];
    int t = threadIdx.x;
    int base = blockIdx.x * CHUNK_E;
    int nend = N_EDGES - base; if (nend > CHUNK_E) nend = CHUNK_E;
    hist[t] = 0;
    __syncthreads();
    for (int i = t; i < nend; i += BINA_T)
        atomicAdd(&hist[rows[base + i] / CB_ROWS], 1);
    __syncthreads();
    cnt[blockIdx.x * NCB + t] = hist[t];
}

// ---------------------------------------------------------------------------
// build 2: per-bucket exclusive scan over the 586 chunk counts (in-place:
// cnt[w][b] <- relative base), bucket total -> stored[b]. One wg per bucket.
// ---------------------------------------------------------------------------
__global__ void __launch_bounds__(BINA_T)
binA_scan_kernel(int* __restrict__ cnt, int* __restrict__ stored) {
    __shared__ int lds[BINA_T];
    int b = blockIdx.x, t = threadIdx.x;
    int w0 = 3 * t;
    int v0 = (w0     < NCHUNK) ? cnt[(w0    ) * NCB + b] : 0;
    int v1 = (w0 + 1 < NCHUNK) ? cnt[(w0 + 1) * NCB + b] : 0;
    int v2 = (w0 + 2 < NCHUNK) ? cnt[(w0 + 2) * NCB + b] : 0;
    lds[t] = v0 + v1 + v2;
    __syncthreads();
    for (int off = 1; off < BINA_T; off <<= 1) {     // Hillis inclusive
        int x = lds[t];
        int y = (t >= off) ? lds[t - off] : 0;
        __syncthreads();
        lds[t] = x + y;
        __syncthreads();
    }
    int excl = (t == 0) ? 0 : lds[t - 1];
    if (w0     < NCHUNK) cnt[(w0    ) * NCB + b] = excl;
    if (w0 + 1 < NCHUNK) cnt[(w0 + 1) * NCB + b] = excl + v0;
    if (w0 + 2 < NCHUNK) cnt[(w0 + 2) * NCB + b] = excl + v0 + v1;
    if (t == BINA_T - 1) stored[b] = lds[BINA_T - 1];
}

// ---------------------------------------------------------------------------
// build 3: scan bucket totals -> csr_base (exact bucket regions, no caps).
// ---------------------------------------------------------------------------
__global__ void __launch_bounds__(NCB)
cb_scan_kernel(const int* __restrict__ stored, int* __restrict__ csr_base,
               int* __restrict__ row_ptr) {
    __shared__ int lds[NCB];
    int t = threadIdx.x;
    lds[t] = stored[t];
    __syncthreads();
    for (int off = 1; off < NCB; off <<= 1) {
        int x = lds[t];
        int y = (t >= off) ? lds[t - off] : 0;
        __syncthreads();
        lds[t] = x + y;
        __syncthreads();
    }
    csr_base[t] = (t == 0) ? 0 : lds[t - 1];
    if (t == 0) { csr_base[NCB] = lds[NCB - 1]; row_ptr[N_NODES] = N_EDGES; }
}

// ---------------------------------------------------------------------------
// build 4: write packed (row_local<<18 | col, val) to its exact reserved
// slot: csr_base[b] + rel[chunk][b] + LDS-local offset. Zero global atomics.
// ---------------------------------------------------------------------------
__global__ void __launch_bounds__(BINA_T)
binA_write_kernel(const int* __restrict__ rows, const int* __restrict__ cols,
                  const float* __restrict__ vals,
                  const int* __restrict__ cnt, const int* __restrict__ csr_base,
                  uint2* __restrict__ tmp) {
    __shared__ int offs[NCB];
    int t = threadIdx.x;
    int base = blockIdx.x * CHUNK_E;
    int nend = N_EDGES - base; if (nend > CHUNK_E) nend = CHUNK_E;
    offs[t] = csr_base[t] + cnt[blockIdx.x * NCB + t];
    __syncthreads();
    for (int i = t; i < nend; i += BINA_T) {
        int e = base + i;
        int r = rows[e];
        unsigned c = (unsigned)cols[e];
        unsigned v = __float_as_uint(vals[e]);
        int b = r / CB_ROWS;
        int p = atomicAdd(&offs[b], 1);
        tmp[p] = make_uint2(((unsigned)(r - b * CB_ROWS) << 18) | c, v);
    }
}

// ---------------------------------------------------------------------------
// passB: one workgroup per coarse bucket. LDS row-degree count -> LDS scan ->
// row_ptr write -> scatter bucket's tmp interval into final CSR order with
// LDS-only cursors.
// ---------------------------------------------------------------------------
__global__ void __launch_bounds__(PB_T)
passB_kernel(const int* __restrict__ csr_base, const uint2* __restrict__ tmp,
             uint2* __restrict__ edges, int* __restrict__ row_ptr) {
    __shared__ int sdeg[PB_T];
    __shared__ int scur[CB_ROWS];
    int b = blockIdx.x, t = threadIdx.x;
    int cb = csr_base[b];
    int n  = csr_base[b + 1] - cb;
    const uint2* tb = tmp + cb;
    sdeg[t] = 0;
    __syncthreads();
    for (int i = t; i < n; i += PB_T)
        atomicAdd(&sdeg[tb[i].x >> 18], 1);
    __syncthreads();
    for (int off = 1; off < PB_T; off <<= 1) {       // inclusive scan
        int x = sdeg[t];
        int y = (t >= off) ? sdeg[t - off] : 0;
        __syncthreads();
        sdeg[t] = x + y;
        __syncthreads();
    }
    int excl = (t == 0) ? 0 : sdeg[t - 1];
    int gr = b * CB_ROWS + t;
    if (t < CB_ROWS && gr < N_NODES) {
        row_ptr[gr] = cb + excl;
        scur[t] = cb + excl;
    }
    __syncthreads();
    for (int i = t; i < n; i += PB_T) {
        uint2 ed = tb[i];
        int p = atomicAdd(&scur[ed.x >> 18], 1);
        edges[p] = make_uint2(ed.x & 0x3FFFFu, ed.y);
    }
}

// ---------------------------------------------------------------------------
// float4-lane CSR SpMM: one wave per row. lane = (g, dq): g = lane>>4 picks
// one of 4 edges per step, dq = lane&15 owns dim quad. Edge stream loaded
// non-temporally (read-once) to keep L2 capacity for the gather table.
// ---------------------------------------------------------------------------
__device__ __forceinline__ void fma4(float4& a, float w, float4 v) {
    a.x += w * v.x; a.y += w * v.y; a.z += w * v.z; a.w += w * v.w;
}

__device__ __forceinline__ uint2 nt_edge(const uint2* p) {
    unsigned long long u = __builtin_nontemporal_load((const unsigned long long*)p);
    return make_uint2((unsigned)u, (unsigned)(u >> 32));
}

__global__ void __launch_bounds__(256)
spmm_csr_kernel(const int* __restrict__ row_ptr,
                const uint2* __restrict__ edges,
                const float* __restrict__ hin,
                float* __restrict__ hout) {
    int wave = (blockIdx.x * blockDim.x + threadIdx.x) >> 6;
    int lane = threadIdx.x & 63;
    if (wave >= N_NODES) return;
    int g  = lane >> 4;
    int dq = lane & 15;
    const float4* __restrict__ hin4 = (const float4*)hin;
    int start = row_ptr[wave];
    int end   = row_ptr[wave + 1];
    float4 a0 = make_float4(0.f, 0.f, 0.f, 0.f);
    float4 a1 = a0, a2 = a0, a3 = a0;
    int e = start;
    for (; e + 16 <= end; e += 16) {
        uint2 e0 = nt_edge(edges + e + g);
        uint2 e1 = nt_edge(edges + e + 4 + g);
        uint2 e2 = nt_edge(edges + e + 8 + g);
        uint2 e3 = nt_edge(edges + e + 12 + g);
        float4 v0 = hin4[(int)e0.x * 16 + dq];
        float4 v1 = hin4[(int)e1.x * 16 + dq];
        float4 v2 = hin4[(int)e2.x * 16 + dq];
        float4 v3 = hin4[(int)e3.x * 16 + dq];
        fma4(a0, __uint_as_float(e0.y), v0);
        fma4(a1, __uint_as_float(e1.y), v1);
        fma4(a2, __uint_as_float(e2.y), v2);
        fma4(a3, __uint_as_float(e3.y), v3);
    }
    for (; e < end; e += 4) {
        int ei = e + g;                               // uniform per 16-lane group
        uint2 ed = (ei < end) ? edges[ei] : make_uint2(0u, 0u);
        float4 v = hin4[(int)ed.x * 16 + dq];         // w = 0 -> no contribution
        fma4(a0, __uint_as_float(ed.y), v);
    }
    float4 s = make_float4((a0.x + a1.x) + (a2.x + a3.x),
                           (a0.y + a1.y) + (a2.y + a3.y),
                           (a0.z + a1.z) + (a2.z + a3.z),
                           (a0.w + a1.w) + (a2.w + a3.w));
    s.x += __shfl_xor(s.x, 16); s.y += __shfl_xor(s.y, 16);
    s.z += __shfl_xor(s.z, 16); s.w += __shfl_xor(s.w, 16);
    s.x += __shfl_xor(s.x, 32); s.y += __shfl_xor(s.y, 32);
    s.z += __shfl_xor(s.z, 32); s.w += __shfl_xor(s.w, 32);
    if (g == 0) ((float4*)hout)[wave * 16 + dq] = s;
}

// ---------------------------------------------------------------------------
// float4-lane CSR SpMM (last layer) fused with h_sum = ego + h1 + h2 + h3
// ---------------------------------------------------------------------------
__global__ void __launch_bounds__(256)
spmm_csr_fused_kernel(const int* __restrict__ row_ptr,
                      const uint2* __restrict__ edges,
                      const float* __restrict__ h2,      // gather source
                      const float* __restrict__ ego,
                      const float* __restrict__ h1,
                      float* __restrict__ h3,
                      float* __restrict__ hsum) {
    int wave = (blockIdx.x * blockDim.x + threadIdx.x) >> 6;
    int lane = threadIdx.x & 63;
    if (wave >= N_NODES) return;
    int g  = lane >> 4;
    int dq = lane & 15;
    const float4* __restrict__ h24 = (const float4*)h2;
    int start = row_ptr[wave];
    int end   = row_ptr[wave + 1];
    float4 a0 = make_float4(0.f, 0.f, 0.f, 0.f);
    float4 a1 = a0, a2 = a0, a3 = a0;
    int e = start;
    for (; e + 16 <= end; e += 16) {
        uint2 e0 = nt_edge(edges + e + g);
        uint2 e1 = nt_edge(edges + e + 4 + g);
        uint2 e2 = nt_edge(edges + e + 8 + g);
        uint2 e3 = nt_edge(edges + e + 12 + g);
        float4 v0 = h24[(int)e0.x * 16 + dq];
        float4 v1 = h24[(int)e1.x * 16 + dq];
        float4 v2 = h24[(int)e2.x * 16 + dq];
        float4 v3 = h24[(int)e3.x * 16 + dq];
        fma4(a0, __uint_as_float(e0.y), v0);
        fma4(a1, __uint_as_float(e1.y), v1);
        fma4(a2, __uint_as_float(e2.y), v2);
        fma4(a3, __uint_as_float(e3.y), v3);
    }
    for (; e < end; e += 4) {
        int ei = e + g;
        uint2 ed = (ei < end) ? edges[ei] : make_uint2(0u, 0u);
        float4 v = h24[(int)ed.x * 16 + dq];
        fma4(a0, __uint_as_float(ed.y), v);
    }
    float4 s = make_float4((a0.x + a1.x) + (a2.x + a3.x),
                           (a0.y + a1.y) + (a2.y + a3.y),
                           (a0.z + a1.z) + (a2.z + a3.z),
                           (a0.w + a1.w) + (a2.w + a3.w));
    s.x += __shfl_xor(s.x, 16); s.y += __shfl_xor(s.y, 16);
    s.z += __shfl_xor(s.z, 16); s.w += __shfl_xor(s.w, 16);
    s.x += __shfl_xor(s.x, 32); s.y += __shfl_xor(s.y, 32);
    s.z += __shfl_xor(s.z, 32); s.w += __shfl_xor(s.w, 32);
    if (g == 0) {
        int o = wave * 16 + dq;
        float4 E  = ((const float4*)ego)[o];
        float4 H1 = ((const float4*)h1)[o];
        float4 H2 = ((const float4*)h2)[o];
        ((float4*)h3)[o] = s;
        ((float4*)hsum)[o] = make_float4(E.x + H1.x + H2.x + s.x,
                                         E.y + H1.y + H2.y + s.y,
                                         E.z + H1.z + H2.z + s.z,
                                         E.w + H1.w + H2.w + s.w);
    }
}

// ---------------------------------------------------------------------------
// Fallback path (used only if ws_size too small for CSR build)
// ---------------------------------------------------------------------------
__global__ void spmm_atomic_kernel(const int* __restrict__ rows,
                                   const int* __restrict__ cols,
                                   const float* __restrict__ vals,
                                   const float* __restrict__ hin,
                                   float* __restrict__ hout) {
    int e = blockIdx.x * 4 + (threadIdx.x >> 6);
    int d = threadIdx.x & 63;
    if (e < N_EDGES) {
        atomicAdd(&hout[rows[e] * DIM + d], vals[e] * hin[cols[e] * DIM + d]);
    }
}

__global__ void zero_f_kernel(float* __restrict__ p, long long n) {
    long long i = (long long)blockIdx.x * blockDim.x + threadIdx.x;
    if (i < n) p[i] = 0.f;
}

__global__ void sum_kernel(const float4* __restrict__ a,
                           const float4* __restrict__ b,
                           const float4* __restrict__ c,
                           const float4* __restrict__ d,
                           float4* __restrict__ out) {
    int i = blockIdx.x * blockDim.x + threadIdx.x;
    if (i < (int)(NF / 4)) {
        float4 x = a[i], y = b[i], z = c[i], w = d[i];
        out[i] = make_float4(x.x + y.x + z.x + w.x,
                             x.y + y.y + z.y + w.y,
                             x.z + y.z + z.z + w.z,
                             x.w + y.w + z.w + w.w);
    }
}

extern "C" void kernel_launch(void* const* d_in, const int* in_sizes, int n_in,
                              void* d_out, int out_size, void* d_ws, size_t ws_size,
                              hipStream_t stream) {
    const float* user = (const float*)d_in[0];
    const float* item = (const float*)d_in[1];
    const float* vals = (const float*)d_in[2];
    const int*   rows = (const int*)d_in[3];
    const int*   cols = (const int*)d_in[4];

    float* out  = (float*)d_out;
    float* hsum = out;
    float* ego  = out + NF;
    float* h1   = out + 2 * NF;
    float* h2   = out + 3 * NF;
    float* h3   = out + 4 * NF;

    const int totF4 = (int)(NF / 4);

    concat_kernel<<<(totF4 + 255) / 256, 256, 0, stream>>>(
        (const float4*)user, (const float4*)item, (float4*)ego);

    // workspace: edges | cnt[586*256] | row_ptr | stored | csr_base
    size_t need = (size_t)N_EDGES * 8
                + ((size_t)NCHUNK * NCB + (size_t)N_NODES + 2 + NCB + NCB + 2 + 16) * 4;

    if (ws_size >= need) {
        uint2* edges    = (uint2*)d_ws;
        int*   cnt      = (int*)(edges + N_EDGES);
        int*   row_ptr  = cnt + (size_t)NCHUNK * NCB;
        int*   stored   = row_ptr + (N_NODES + 2);
        int*   csr_base = stored + NCB;
        // tmp staging lives in the (still-dead) h1 output region:
        // N_EDGES*8 = 38,400,000 B <= NF*4 = 38,400,256 B
        uint2* tmp      = (uint2*)h1;

        binA_count_kernel<<<NCHUNK, BINA_T, 0, stream>>>(rows, cnt);
        binA_scan_kernel<<<NCB, BINA_T, 0, stream>>>(cnt, stored);
        cb_scan_kernel<<<1, NCB, 0, stream>>>(stored, csr_base, row_ptr);
        binA_write_kernel<<<NCHUNK, BINA_T, 0, stream>>>(
            rows, cols, vals, cnt, csr_base, tmp);
        passB_kernel<<<NCB, PB_T, 0, stream>>>(csr_base, tmp, edges, row_ptr);

        const int spmmBlocks = (N_NODES * 64 + 255) / 256;  // 1 wave per row
        spmm_csr_kernel<<<spmmBlocks, 256, 0, stream>>>(row_ptr, edges, ego, h1);
        spmm_csr_kernel<<<spmmBlocks, 256, 0, stream>>>(row_ptr, edges, h1,  h2);
        spmm_csr_fused_kernel<<<spmmBlocks, 256, 0, stream>>>(
            row_ptr, edges, h2, ego, h1, h3, hsum);
    } else {
        const long long nz = 3 * NF;
        zero_f_kernel<<<(int)((nz + 255) / 256), 256, 0, stream>>>(h1, nz);
        const int ablocks = (N_EDGES + 3) / 4;
        spmm_atomic_kernel<<<ablocks, 256, 0, stream>>>(rows, cols, vals, ego, h1);
        spmm_atomic_kernel<<<ablocks, 256, 0, stream>>>(rows, cols, vals, h1,  h2);
        spmm_atomic_kernel<<<ablocks, 256, 0, stream>>>(rows, cols, vals, h2,  h3);
        sum_kernel<<<(totF4 + 255) / 256, 256, 0, stream>>>(
            (const float4*)ego, (const float4*)h1, (const float4*)h2, (const float4*)h3,
            (float4*)hsum);
    }
}

// Round 7
// 701.973 us; speedup vs baseline: 1.2812x; 1.2812x over previous
//
#include <hip/hip_runtime.h>
#include <hip/hip_fp16.h>

#define N_USERS 100000
#define N_ITEMS 50000
#define DIM     64
#define N_NODES (N_USERS + N_ITEMS + 1)   /* 150001 */
#define N_EDGES 4800000

static constexpr long long NF = (long long)N_NODES * DIM;   // 9,600,064 floats per tensor

// ------------------- coarse-bucket counting-sort geometry -------------------
#define NCB      256                       /* coarse buckets                  */
#define CB_ROWS  586                       /* rows per bucket: 586*256=150016 */
#define CHUNK_E  8192                      /* edges per chunk                 */
#define BINA_T   256
#define NCHUNK   ((N_EDGES + CHUNK_E - 1) / CHUNK_E)   /* 586 */
#define PB_T     1024

// ---------------------------------------------------------------------------
// ego = concat(user_emb, item_emb); also emits fp16 copy for the gather table
// ---------------------------------------------------------------------------
__device__ __forceinline__ uint2 pack_half4(float4 s) {
    uint2 pk;
    *(__half2*)&pk.x = __float22half2_rn(make_float2(s.x, s.y));
    *(__half2*)&pk.y = __float22half2_rn(make_float2(s.z, s.w));
    return pk;
}

__global__ void concat16_kernel(const float4* __restrict__ user,
                                const float4* __restrict__ item,
                                float4* __restrict__ ego,
                                uint2* __restrict__ ego16) {
    int i = blockIdx.x * blockDim.x + threadIdx.x;
    const int userF4 = N_USERS * DIM / 4;
    const int totF4  = (int)(NF / 4);
    if (i < totF4) {
        float4 v = (i < userF4) ? user[i] : item[i - userF4];
        ego[i]   = v;
        ego16[i] = pack_half4(v);
    }
}

__global__ void concat_kernel(const float4* __restrict__ user,
                              const float4* __restrict__ item,
                              float4* __restrict__ ego) {
    int i = blockIdx.x * blockDim.x + threadIdx.x;
    const int userF4 = N_USERS * DIM / 4;
    const int totF4  = (int)(NF / 4);
    if (i < userF4)      ego[i] = user[i];
    else if (i < totF4)  ego[i] = item[i - userF4];
}

// ---------------------------------------------------------------------------
// build 1: per-chunk bucket histogram -> cnt[chunk][bucket]. LDS atomics only.
// ---------------------------------------------------------------------------
__global__ void __launch_bounds__(BINA_T)
binA_count_kernel(const int* __restrict__ rows, int* __restrict__ cnt) {
    __shared__ int hist[NCB];
    int t = threadIdx.x;
    int base = blockIdx.x * CHUNK_E;
    int nend = N_EDGES - base; if (nend > CHUNK_E) nend = CHUNK_E;
    hist[t] = 0;
    __syncthreads();
    for (int i = t; i < nend; i += BINA_T)
        atomicAdd(&hist[rows[base + i] / CB_ROWS], 1);
    __syncthreads();
    cnt[blockIdx.x * NCB + t] = hist[t];
}

// ---------------------------------------------------------------------------
// build 2: per-bucket exclusive scan over chunk counts (in-place), totals.
// ---------------------------------------------------------------------------
__global__ void __launch_bounds__(BINA_T)
binA_scan_kernel(int* __restrict__ cnt, int* __restrict__ stored) {
    __shared__ int lds[BINA_T];
    int b = blockIdx.x, t = threadIdx.x;
    int w0 = 3 * t;
    int v0 = (w0     < NCHUNK) ? cnt[(w0    ) * NCB + b] : 0;
    int v1 = (w0 + 1 < NCHUNK) ? cnt[(w0 + 1) * NCB + b] : 0;
    int v2 = (w0 + 2 < NCHUNK) ? cnt[(w0 + 2) * NCB + b] : 0;
    lds[t] = v0 + v1 + v2;
    __syncthreads();
    for (int off = 1; off < BINA_T; off <<= 1) {     // Hillis inclusive
        int x = lds[t];
        int y = (t >= off) ? lds[t - off] : 0;
        __syncthreads();
        lds[t] = x + y;
        __syncthreads();
    }
    int excl = (t == 0) ? 0 : lds[t - 1];
    if (w0     < NCHUNK) cnt[(w0    ) * NCB + b] = excl;
    if (w0 + 1 < NCHUNK) cnt[(w0 + 1) * NCB + b] = excl + v0;
    if (w0 + 2 < NCHUNK) cnt[(w0 + 2) * NCB + b] = excl + v0 + v1;
    if (t == BINA_T - 1) stored[b] = lds[BINA_T - 1];
}

// ---------------------------------------------------------------------------
// build 3: scan bucket totals -> csr_base (exact bucket regions).
// ---------------------------------------------------------------------------
__global__ void __launch_bounds__(NCB)
cb_scan_kernel(const int* __restrict__ stored, int* __restrict__ csr_base,
               int* __restrict__ row_ptr) {
    __shared__ int lds[NCB];
    int t = threadIdx.x;
    lds[t] = stored[t];
    __syncthreads();
    for (int off = 1; off < NCB; off <<= 1) {
        int x = lds[t];
        int y = (t >= off) ? lds[t - off] : 0;
        __syncthreads();
        lds[t] = x + y;
        __syncthreads();
    }
    csr_base[t] = (t == 0) ? 0 : lds[t - 1];
    if (t == 0) { csr_base[NCB] = lds[NCB - 1]; row_ptr[N_NODES] = N_EDGES; }
}

// ---------------------------------------------------------------------------
// build 4: write packed (row_local<<18 | col, val) to exact reserved slot.
// ---------------------------------------------------------------------------
__global__ void __launch_bounds__(BINA_T)
binA_write_kernel(const int* __restrict__ rows, const int* __restrict__ cols,
                  const float* __restrict__ vals,
                  const int* __restrict__ cnt, const int* __restrict__ csr_base,
                  uint2* __restrict__ tmp) {
    __shared__ int offs[NCB];
    int t = threadIdx.x;
    int base = blockIdx.x * CHUNK_E;
    int nend = N_EDGES - base; if (nend > CHUNK_E) nend = CHUNK_E;
    offs[t] = csr_base[t] + cnt[blockIdx.x * NCB + t];
    __syncthreads();
    for (int i = t; i < nend; i += BINA_T) {
        int e = base + i;
        int r = rows[e];
        unsigned c = (unsigned)cols[e];
        unsigned v = __float_as_uint(vals[e]);
        int b = r / CB_ROWS;
        int p = atomicAdd(&offs[b], 1);
        tmp[p] = make_uint2(((unsigned)(r - b * CB_ROWS) << 18) | c, v);
    }
}

// ---------------------------------------------------------------------------
// passB: per-bucket LDS degree count -> scan -> row_ptr -> in-order scatter.
// ---------------------------------------------------------------------------
__global__ void __launch_bounds__(PB_T)
passB_kernel(const int* __restrict__ csr_base, const uint2* __restrict__ tmp,
             uint2* __restrict__ edges, int* __restrict__ row_ptr) {
    __shared__ int sdeg[PB_T];
    __shared__ int scur[CB_ROWS];
    int b = blockIdx.x, t = threadIdx.x;
    int cb = csr_base[b];
    int n  = csr_base[b + 1] - cb;
    const uint2* tb = tmp + cb;
    sdeg[t] = 0;
    __syncthreads();
    for (int i = t; i < n; i += PB_T)
        atomicAdd(&sdeg[tb[i].x >> 18], 1);
    __syncthreads();
    for (int off = 1; off < PB_T; off <<= 1) {       // inclusive scan
        int x = sdeg[t];
        int y = (t >= off) ? sdeg[t - off] : 0;
        __syncthreads();
        sdeg[t] = x + y;
        __syncthreads();
    }
    int excl = (t == 0) ? 0 : sdeg[t - 1];
    int gr = b * CB_ROWS + t;
    if (t < CB_ROWS && gr < N_NODES) {
        row_ptr[gr] = cb + excl;
        scur[t] = cb + excl;
    }
    __syncthreads();
    for (int i = t; i < n; i += PB_T) {
        uint2 ed = tb[i];
        int p = atomicAdd(&scur[ed.x >> 18], 1);
        edges[p] = make_uint2(ed.x & 0x3FFFFu, ed.y);
    }
}

// ---------------------------------------------------------------------------
// SpMM helpers
// ---------------------------------------------------------------------------
__device__ __forceinline__ void fma4(float4& a, float w, float4 v) {
    a.x += w * v.x; a.y += w * v.y; a.z += w * v.z; a.w += w * v.w;
}
__device__ __forceinline__ void fma16(float4& a, float w, uint2 u) {
    float2 lo = __half22float2(*(const __half2*)&u.x);
    float2 hi = __half22float2(*(const __half2*)&u.y);
    a.x += w * lo.x; a.y += w * lo.y; a.z += w * hi.x; a.w += w * hi.y;
}

// ---------------------------------------------------------------------------
// fp16-gather CSR SpMM: one wave per row; lane = (g, dq). Each 16-lane group
// reads a FULL 128B fp16 row per gather (uint2 = 4 halves per lane).
// Gather traffic halves vs fp32 table. Output: exact fp32 + fp16 copy for
// the next layer.
// ---------------------------------------------------------------------------
__global__ void __launch_bounds__(256)
spmm16_kernel(const int* __restrict__ row_ptr,
              const uint2* __restrict__ edges,
              const uint2* __restrict__ hin16,     // [N_NODES*16] uint2
              float* __restrict__ hout,
              uint2* __restrict__ hout16) {
    int wave = (blockIdx.x * blockDim.x + threadIdx.x) >> 6;
    int lane = threadIdx.x & 63;
    if (wave >= N_NODES) return;
    int g  = lane >> 4;
    int dq = lane & 15;
    int start = row_ptr[wave];
    int end   = row_ptr[wave + 1];
    float4 a0 = make_float4(0.f, 0.f, 0.f, 0.f);
    float4 a1 = a0, a2 = a0, a3 = a0;
    int e = start;
    for (; e + 16 <= end; e += 16) {
        uint2 e0 = edges[e + g];
        uint2 e1 = edges[e + 4 + g];
        uint2 e2 = edges[e + 8 + g];
        uint2 e3 = edges[e + 12 + g];
        uint2 v0 = hin16[(int)e0.x * 16 + dq];
        uint2 v1 = hin16[(int)e1.x * 16 + dq];
        uint2 v2 = hin16[(int)e2.x * 16 + dq];
        uint2 v3 = hin16[(int)e3.x * 16 + dq];
        fma16(a0, __uint_as_float(e0.y), v0);
        fma16(a1, __uint_as_float(e1.y), v1);
        fma16(a2, __uint_as_float(e2.y), v2);
        fma16(a3, __uint_as_float(e3.y), v3);
    }
    for (; e < end; e += 4) {
        int ei = e + g;                               // uniform per 16-lane group
        uint2 ed = (ei < end) ? edges[ei] : make_uint2(0u, 0u);
        uint2 v = hin16[(int)ed.x * 16 + dq];         // w = 0 -> no contribution
        fma16(a0, __uint_as_float(ed.y), v);
    }
    float4 s = make_float4((a0.x + a1.x) + (a2.x + a3.x),
                           (a0.y + a1.y) + (a2.y + a3.y),
                           (a0.z + a1.z) + (a2.z + a3.z),
                           (a0.w + a1.w) + (a2.w + a3.w));
    s.x += __shfl_xor(s.x, 16); s.y += __shfl_xor(s.y, 16);
    s.z += __shfl_xor(s.z, 16); s.w += __shfl_xor(s.w, 16);
    s.x += __shfl_xor(s.x, 32); s.y += __shfl_xor(s.y, 32);
    s.z += __shfl_xor(s.z, 32); s.w += __shfl_xor(s.w, 32);
    if (g == 0) {
        int o = wave * 16 + dq;
        ((float4*)hout)[o] = s;
        hout16[o] = pack_half4(s);
    }
}

// ---------------------------------------------------------------------------
// fp16-gather CSR SpMM (last layer) fused with h_sum = ego + h1 + h2 + h3.
// Epilogue sums the EXACT fp32 tensors.
// ---------------------------------------------------------------------------
__global__ void __launch_bounds__(256)
spmm16_fused_kernel(const int* __restrict__ row_ptr,
                    const uint2* __restrict__ edges,
                    const uint2* __restrict__ hin16,   // h2 fp16 copy
                    const float* __restrict__ ego,
                    const float* __restrict__ h1,
                    const float* __restrict__ h2,
                    float* __restrict__ h3,
                    float* __restrict__ hsum) {
    int wave = (blockIdx.x * blockDim.x + threadIdx.x) >> 6;
    int lane = threadIdx.x & 63;
    if (wave >= N_NODES) return;
    int g  = lane >> 4;
    int dq = lane & 15;
    int start = row_ptr[wave];
    int end   = row_ptr[wave + 1];
    float4 a0 = make_float4(0.f, 0.f, 0.f, 0.f);
    float4 a1 = a0, a2 = a0, a3 = a0;
    int e = start;
    for (; e + 16 <= end; e += 16) {
        uint2 e0 = edges[e + g];
        uint2 e1 = edges[e + 4 + g];
        uint2 e2 = edges[e + 8 + g];
        uint2 e3 = edges[e + 12 + g];
        uint2 v0 = hin16[(int)e0.x * 16 + dq];
        uint2 v1 = hin16[(int)e1.x * 16 + dq];
        uint2 v2 = hin16[(int)e2.x * 16 + dq];
        uint2 v3 = hin16[(int)e3.x * 16 + dq];
        fma16(a0, __uint_as_float(e0.y), v0);
        fma16(a1, __uint_as_float(e1.y), v1);
        fma16(a2, __uint_as_float(e2.y), v2);
        fma16(a3, __uint_as_float(e3.y), v3);
    }
    for (; e < end; e += 4) {
        int ei = e + g;
        uint2 ed = (ei < end) ? edges[ei] : make_uint2(0u, 0u);
        uint2 v = hin16[(int)ed.x * 16 + dq];
        fma16(a0, __uint_as_float(ed.y), v);
    }
    float4 s = make_float4((a0.x + a1.x) + (a2.x + a3.x),
                           (a0.y + a1.y) + (a2.y + a3.y),
                           (a0.z + a1.z) + (a2.z + a3.z),
                           (a0.w + a1.w) + (a2.w + a3.w));
    s.x += __shfl_xor(s.x, 16); s.y += __shfl_xor(s.y, 16);
    s.z += __shfl_xor(s.z, 16); s.w += __shfl_xor(s.w, 16);
    s.x += __shfl_xor(s.x, 32); s.y += __shfl_xor(s.y, 32);
    s.z += __shfl_xor(s.z, 32); s.w += __shfl_xor(s.w, 32);
    if (g == 0) {
        int o = wave * 16 + dq;
        float4 E  = ((const float4*)ego)[o];
        float4 H1 = ((const float4*)h1)[o];
        float4 H2 = ((const float4*)h2)[o];
        ((float4*)h3)[o] = s;
        ((float4*)hsum)[o] = make_float4(E.x + H1.x + H2.x + s.x,
                                         E.y + H1.y + H2.y + s.y,
                                         E.z + H1.z + H2.z + s.z,
                                         E.w + H1.w + H2.w + s.w);
    }
}

// ---------------------------------------------------------------------------
// fp32-gather variants (tier-2 fallback when workspace can't hold fp16 tables)
// ---------------------------------------------------------------------------
__global__ void __launch_bounds__(256)
spmm_csr_kernel(const int* __restrict__ row_ptr,
                const uint2* __restrict__ edges,
                const float* __restrict__ hin,
                float* __restrict__ hout) {
    int wave = (blockIdx.x * blockDim.x + threadIdx.x) >> 6;
    int lane = threadIdx.x & 63;
    if (wave >= N_NODES) return;
    int g  = lane >> 4;
    int dq = lane & 15;
    const float4* __restrict__ hin4 = (const float4*)hin;
    int start = row_ptr[wave];
    int end   = row_ptr[wave + 1];
    float4 a0 = make_float4(0.f, 0.f, 0.f, 0.f);
    float4 a1 = a0, a2 = a0, a3 = a0;
    int e = start;
    for (; e + 16 <= end; e += 16) {
        uint2 e0 = edges[e + g];
        uint2 e1 = edges[e + 4 + g];
        uint2 e2 = edges[e + 8 + g];
        uint2 e3 = edges[e + 12 + g];
        float4 v0 = hin4[(int)e0.x * 16 + dq];
        float4 v1 = hin4[(int)e1.x * 16 + dq];
        float4 v2 = hin4[(int)e2.x * 16 + dq];
        float4 v3 = hin4[(int)e3.x * 16 + dq];
        fma4(a0, __uint_as_float(e0.y), v0);
        fma4(a1, __uint_as_float(e1.y), v1);
        fma4(a2, __uint_as_float(e2.y), v2);
        fma4(a3, __uint_as_float(e3.y), v3);
    }
    for (; e < end; e += 4) {
        int ei = e + g;
        uint2 ed = (ei < end) ? edges[ei] : make_uint2(0u, 0u);
        float4 v = hin4[(int)ed.x * 16 + dq];
        fma4(a0, __uint_as_float(ed.y), v);
    }
    float4 s = make_float4((a0.x + a1.x) + (a2.x + a3.x),
                           (a0.y + a1.y) + (a2.y + a3.y),
                           (a0.z + a1.z) + (a2.z + a3.z),
                           (a0.w + a1.w) + (a2.w + a3.w));
    s.x += __shfl_xor(s.x, 16); s.y += __shfl_xor(s.y, 16);
    s.z += __shfl_xor(s.z, 16); s.w += __shfl_xor(s.w, 16);
    s.x += __shfl_xor(s.x, 32); s.y += __shfl_xor(s.y, 32);
    s.z += __shfl_xor(s.z, 32); s.w += __shfl_xor(s.w, 32);
    if (g == 0) ((float4*)hout)[wave * 16 + dq] = s;
}

__global__ void __launch_bounds__(256)
spmm_csr_fused_kernel(const int* __restrict__ row_ptr,
                      const uint2* __restrict__ edges,
                      const float* __restrict__ h2,
                      const float* __restrict__ ego,
                      const float* __restrict__ h1,
                      float* __restrict__ h3,
                      float* __restrict__ hsum) {
    int wave = (blockIdx.x * blockDim.x + threadIdx.x) >> 6;
    int lane = threadIdx.x & 63;
    if (wave >= N_NODES) return;
    int g  = lane >> 4;
    int dq = lane & 15;
    const float4* __restrict__ h24 = (const float4*)h2;
    int start = row_ptr[wave];
    int end   = row_ptr[wave + 1];
    float4 a0 = make_float4(0.f, 0.f, 0.f, 0.f);
    float4 a1 = a0, a2 = a0, a3 = a0;
    int e = start;
    for (; e + 16 <= end; e += 16) {
        uint2 e0 = edges[e + g];
        uint2 e1 = edges[e + 4 + g];
        uint2 e2 = edges[e + 8 + g];
        uint2 e3 = edges[e + 12 + g];
        float4 v0 = h24[(int)e0.x * 16 + dq];
        float4 v1 = h24[(int)e1.x * 16 + dq];
        float4 v2 = h24[(int)e2.x * 16 + dq];
        float4 v3 = h24[(int)e3.x * 16 + dq];
        fma4(a0, __uint_as_float(e0.y), v0);
        fma4(a1, __uint_as_float(e1.y), v1);
        fma4(a2, __uint_as_float(e2.y), v2);
        fma4(a3, __uint_as_float(e3.y), v3);
    }
    for (; e < end; e += 4) {
        int ei = e + g;
        uint2 ed = (ei < end) ? edges[ei] : make_uint2(0u, 0u);
        float4 v = h24[(int)ed.x * 16 + dq];
        fma4(a0, __uint_as_float(ed.y), v);
    }
    float4 s = make_float4((a0.x + a1.x) + (a2.x + a3.x),
                           (a0.y + a1.y) + (a2.y + a3.y),
                           (a0.z + a1.z) + (a2.z + a3.z),
                           (a0.w + a1.w) + (a2.w + a3.w));
    s.x += __shfl_xor(s.x, 16); s.y += __shfl_xor(s.y, 16);
    s.z += __shfl_xor(s.z, 16); s.w += __shfl_xor(s.w, 16);
    s.x += __shfl_xor(s.x, 32); s.y += __shfl_xor(s.y, 32);
    s.z += __shfl_xor(s.z, 32); s.w += __shfl_xor(s.w, 32);
    if (g == 0) {
        int o = wave * 16 + dq;
        float4 E  = ((const float4*)ego)[o];
        float4 H1 = ((const float4*)h1)[o];
        float4 H2 = ((const float4*)h2)[o];
        ((float4*)h3)[o] = s;
        ((float4*)hsum)[o] = make_float4(E.x + H1.x + H2.x + s.x,
                                         E.y + H1.y + H2.y + s.y,
                                         E.z + H1.z + H2.z + s.z,
                                         E.w + H1.w + H2.w + s.w);
    }
}

// ---------------------------------------------------------------------------
// tier-3 fallback (tiny workspace): fp32 atomics
// ---------------------------------------------------------------------------
__global__ void spmm_atomic_kernel(const int* __restrict__ rows,
                                   const int* __restrict__ cols,
                                   const float* __restrict__ vals,
                                   const float* __restrict__ hin,
                                   float* __restrict__ hout) {
    int e = blockIdx.x * 4 + (threadIdx.x >> 6);
    int d = threadIdx.x & 63;
    if (e < N_EDGES) {
        atomicAdd(&hout[rows[e] * DIM + d], vals[e] * hin[cols[e] * DIM + d]);
    }
}

__global__ void zero_f_kernel(float* __restrict__ p, long long n) {
    long long i = (long long)blockIdx.x * blockDim.x + threadIdx.x;
    if (i < n) p[i] = 0.f;
}

__global__ void sum_kernel(const float4* __restrict__ a,
                           const float4* __restrict__ b,
                           const float4* __restrict__ c,
                           const float4* __restrict__ d,
                           float4* __restrict__ out) {
    int i = blockIdx.x * blockDim.x + threadIdx.x;
    if (i < (int)(NF / 4)) {
        float4 x = a[i], y = b[i], z = c[i], w = d[i];
        out[i] = make_float4(x.x + y.x + z.x + w.x,
                             x.y + y.y + z.y + w.y,
                             x.z + y.z + z.z + w.z,
                             x.w + y.w + z.w + w.w);
    }
}

extern "C" void kernel_launch(void* const* d_in, const int* in_sizes, int n_in,
                              void* d_out, int out_size, void* d_ws, size_t ws_size,
                              hipStream_t stream) {
    const float* user = (const float*)d_in[0];
    const float* item = (const float*)d_in[1];
    const float* vals = (const float*)d_in[2];
    const int*   rows = (const int*)d_in[3];
    const int*   cols = (const int*)d_in[4];

    float* out  = (float*)d_out;
    float* hsum = out;
    float* ego  = out + NF;
    float* h1   = out + 2 * NF;
    float* h2   = out + 3 * NF;
    float* h3   = out + 4 * NF;

    const int totF4 = (int)(NF / 4);

    const size_t edgesB = (size_t)N_EDGES * 8;
    const size_t h16B   = (size_t)N_NODES * DIM * 2;              // 19,200,128
    const size_t intsB  = ((size_t)NCHUNK * NCB + (size_t)N_NODES + 2
                           + NCB + NCB + 2 + 16) * 4;
    const size_t need32 = edgesB + intsB;                          // ~41 MB
    const size_t need16 = edgesB + 2 * h16B + intsB;               // ~79 MB

    if (ws_size >= need32) {
        uint2* edges = (uint2*)d_ws;
        char*  p     = (char*)(edges + N_EDGES);
        uint2* hA    = nullptr;
        uint2* hB    = nullptr;
        bool   f16   = (ws_size >= need16);
        if (f16) {
            hA = (uint2*)p;  p += h16B;
            hB = (uint2*)p;  p += h16B;
        }
        int* cnt      = (int*)p;
        int* row_ptr  = cnt + (size_t)NCHUNK * NCB;
        int* stored   = row_ptr + (N_NODES + 2);
        int* csr_base = stored + NCB;
        // tmp staging lives in the (still-dead) h1 output region
        uint2* tmp    = (uint2*)h1;

        if (f16) {
            concat16_kernel<<<(totF4 + 255) / 256, 256, 0, stream>>>(
                (const float4*)user, (const float4*)item, (float4*)ego, hA);
        } else {
            concat_kernel<<<(totF4 + 255) / 256, 256, 0, stream>>>(
                (const float4*)user, (const float4*)item, (float4*)ego);
        }

        binA_count_kernel<<<NCHUNK, BINA_T, 0, stream>>>(rows, cnt);
        binA_scan_kernel<<<NCB, BINA_T, 0, stream>>>(cnt, stored);
        cb_scan_kernel<<<1, NCB, 0, stream>>>(stored, csr_base, row_ptr);
        binA_write_kernel<<<NCHUNK, BINA_T, 0, stream>>>(
            rows, cols, vals, cnt, csr_base, tmp);
        passB_kernel<<<NCB, PB_T, 0, stream>>>(csr_base, tmp, edges, row_ptr);

        const int spmmBlocks = (N_NODES * 64 + 255) / 256;  // 1 wave per row
        if (f16) {
            // gather fp16 (128B/row): hA=ego16 -> h1(+hB), hB -> h2(+hA), hA -> h3
            spmm16_kernel<<<spmmBlocks, 256, 0, stream>>>(row_ptr, edges, hA, h1, hB);
            spmm16_kernel<<<spmmBlocks, 256, 0, stream>>>(row_ptr, edges, hB, h2, hA);
            spmm16_fused_kernel<<<spmmBlocks, 256, 0, stream>>>(
                row_ptr, edges, hA, ego, h1, h2, h3, hsum);
        } else {
            spmm_csr_kernel<<<spmmBlocks, 256, 0, stream>>>(row_ptr, edges, ego, h1);
            spmm_csr_kernel<<<spmmBlocks, 256, 0, stream>>>(row_ptr, edges, h1,  h2);
            spmm_csr_fused_kernel<<<spmmBlocks, 256, 0, stream>>>(
                row_ptr, edges, h2, ego, h1, h3, hsum);
        }
    } else {
        concat_kernel<<<(totF4 + 255) / 256, 256, 0, stream>>>(
            (const float4*)user, (const float4*)item, (float4*)ego);
        const long long nz = 3 * NF;
        zero_f_kernel<<<(int)((nz + 255) / 256), 256, 0, stream>>>(h1, nz);
        const int ablocks = (N_EDGES + 3) / 4;
        spmm_atomic_kernel<<<ablocks, 256, 0, stream>>>(rows, cols, vals, ego, h1);
        spmm_atomic_kernel<<<ablocks, 256, 0, stream>>>(rows, cols, vals, h1,  h2);
        spmm_atomic_kernel<<<ablocks, 256, 0, stream>>>(rows, cols, vals, h2,  h3);
        sum_kernel<<<(totF4 + 255) / 256, 256, 0, stream>>>(
            (const float4*)ego, (const float4*)h1, (const float4*)h2, (const float4*)h3,
            (float4*)hsum);
    }
}

// Round 8
// 688.450 us; speedup vs baseline: 1.3064x; 1.0196x over previous
//
#include <hip/hip_runtime.h>
#include <hip/hip_fp16.h>

#define N_USERS 100000
#define N_ITEMS 50000
#define DIM     64
#define N_NODES (N_USERS + N_ITEMS + 1)   /* 150001 */
#define N_EDGES 4800000

static constexpr long long NF = (long long)N_NODES * DIM;   // 9,600,064 floats per tensor

// ------------------- coarse-bucket counting-sort geometry -------------------
#define NCB      256                       /* coarse buckets                  */
#define CB_ROWS  586                       /* rows per bucket: 586*256=150016 */
#define CHUNK_E  4096                      /* edges per chunk (2x parallelism)*/
#define BINA_T   256
#define NCHUNK   ((N_EDGES + CHUNK_E - 1) / CHUNK_E)   /* 1172 */
#define CPT      5                         /* chunks per thread in binA_scan  */
#define PB_T     1024
#define CONCAT_BLK ((int)((NF / 4 + 255) / 256))       /* 9376 */

// ---------------------------------------------------------------------------
// helpers
// ---------------------------------------------------------------------------
__device__ __forceinline__ uint2 pack_half4(float4 s) {
    uint2 pk;
    *(__half2*)&pk.x = __float22half2_rn(make_float2(s.x, s.y));
    *(__half2*)&pk.y = __float22half2_rn(make_float2(s.z, s.w));
    return pk;
}

// exclusive prefix over 256 threads (4 waves). wp = LDS[4]. Contains barrier.
__device__ __forceinline__ int wavescan256_excl(int own, int t, int* wp) {
    int lane = t & 63, wid = t >> 6;
    int v = own;
    #pragma unroll
    for (int off = 1; off < 64; off <<= 1) {
        int y = __shfl_up(v, off);
        if (lane >= off) v += y;
    }
    if (lane == 63) wp[wid] = v;
    __syncthreads();
    int woff = 0;
    #pragma unroll
    for (int w = 0; w < 4; ++w) if (w < wid) woff += wp[w];
    return v + woff - own;
}

// ---------------------------------------------------------------------------
// fused: blocks [0,NCHUNK) = per-chunk bucket histogram (LDS atomics only);
//        blocks [NCHUNK,..) = ego concat (+ optional fp16 copy).
// Overlaps BW-bound concat with latency-bound counting; saves a launch.
// ---------------------------------------------------------------------------
__global__ void __launch_bounds__(BINA_T)
fused_count_concat_kernel(const int* __restrict__ rows, int* __restrict__ cnt,
                          const float4* __restrict__ user,
                          const float4* __restrict__ item,
                          float4* __restrict__ ego, uint2* __restrict__ ego16) {
    __shared__ int hist[NCB];
    int bb = blockIdx.x;
    int t  = threadIdx.x;
    if (bb < NCHUNK) {
        hist[t] = 0;
        __syncthreads();
        int base = bb * CHUNK_E;
        int nend = N_EDGES - base; if (nend > CHUNK_E) nend = CHUNK_E;
        for (int i = t; i < nend; i += BINA_T)
            atomicAdd(&hist[rows[base + i] / CB_ROWS], 1);
        __syncthreads();
        cnt[bb * NCB + t] = hist[t];
    } else {
        int i = (bb - NCHUNK) * BINA_T + t;
        const int userF4 = N_USERS * DIM / 4;
        const int totF4  = (int)(NF / 4);
        if (i < totF4) {
            float4 v = (i < userF4) ? user[i] : item[i - userF4];
            ego[i] = v;
            if (ego16) ego16[i] = pack_half4(v);
        }
    }
}

// ---------------------------------------------------------------------------
// binA_scan: per-bucket exclusive scan over 1172 chunk counts (in-place),
// bucket total -> stored[b]. One wg per bucket; CPT chunks per thread.
// ---------------------------------------------------------------------------
__global__ void __launch_bounds__(BINA_T)
binA_scan_kernel(int* __restrict__ cnt, int* __restrict__ stored) {
    __shared__ int wp[4];
    int b = blockIdx.x, t = threadIdx.x;
    int v[CPT];
    int s = 0;
    #pragma unroll
    for (int i = 0; i < CPT; ++i) {
        int idx = CPT * t + i;
        int x = (idx < NCHUNK) ? cnt[idx * NCB + b] : 0;
        v[i] = s;               // thread-local exclusive prefix
        s += x;
    }
    int excl = wavescan256_excl(s, t, wp);
    #pragma unroll
    for (int i = 0; i < CPT; ++i) {
        int idx = CPT * t + i;
        if (idx < NCHUNK) cnt[idx * NCB + b] = excl + v[i];
    }
    if (t == BINA_T - 1) stored[b] = excl + s;   // inclusive total
}

// ---------------------------------------------------------------------------
// binA_write: csr_base computed locally (scan of stored, 1KB), then write
// packed (row_local<<18 | col, val) to exact reserved slot. No global atomics.
// ---------------------------------------------------------------------------
__global__ void __launch_bounds__(BINA_T)
binA_write_kernel(const int* __restrict__ rows, const int* __restrict__ cols,
                  const float* __restrict__ vals,
                  const int* __restrict__ cnt, const int* __restrict__ stored,
                  uint2* __restrict__ tmp) {
    __shared__ int offs[NCB];
    __shared__ int wp[4];
    int t = threadIdx.x;
    int bb = blockIdx.x;
    int sv = stored[t];
    int csr_b = wavescan256_excl(sv, t, wp);     // exclusive bucket base
    offs[t] = csr_b + cnt[bb * NCB + t];
    __syncthreads();
    int base = bb * CHUNK_E;
    int nend = N_EDGES - base; if (nend > CHUNK_E) nend = CHUNK_E;
    for (int i = t; i < nend; i += BINA_T) {
        int e = base + i;
        int r = rows[e];
        unsigned c = (unsigned)cols[e];
        unsigned v = __float_as_uint(vals[e]);
        int b = r / CB_ROWS;
        int p = atomicAdd(&offs[b], 1);
        tmp[p] = make_uint2(((unsigned)(r - b * CB_ROWS) << 18) | c, v);
    }
}

// ---------------------------------------------------------------------------
// passB: one wg per bucket. Bucket base via LDS reduction of stored[0..b);
// LDS row-degree hist -> shfl wave-scan (2 barriers, was 20) -> row_ptr ->
// scatter into final CSR order with LDS cursors.
// ---------------------------------------------------------------------------
__global__ void __launch_bounds__(PB_T)
passB_kernel(const int* __restrict__ stored, const uint2* __restrict__ tmp,
             uint2* __restrict__ edges, int* __restrict__ row_ptr) {
    __shared__ int sdeg[PB_T];
    __shared__ int scur[CB_ROWS];
    __shared__ int wp16[16];
    __shared__ int cbs;
    int b = blockIdx.x, t = threadIdx.x;
    if (t == 0) cbs = 0;
    sdeg[t] = 0;
    __syncthreads();
    if (t < b) atomicAdd(&cbs, stored[t]);       // bucket base = sum stored[0..b)
    __syncthreads();
    int cb = cbs;
    int n  = stored[b];
    const uint2* tb = tmp + cb;
    for (int i = t; i < n; i += PB_T)
        atomicAdd(&sdeg[tb[i].x >> 18], 1);
    __syncthreads();
    // inclusive scan of sdeg via wave-scan
    int own = sdeg[t];
    int lane = t & 63, wid = t >> 6;
    int v = own;
    #pragma unroll
    for (int off = 1; off < 64; off <<= 1) {
        int y = __shfl_up(v, off);
        if (lane >= off) v += y;
    }
    if (lane == 63) wp16[wid] = v;
    __syncthreads();
    int woff = 0;
    for (int w = 0; w < wid; ++w) woff += wp16[w];
    int excl = v + woff - own;
    int gr = b * CB_ROWS + t;
    if (t < CB_ROWS && gr < N_NODES) {
        row_ptr[gr] = cb + excl;
        scur[t] = cb + excl;
    }
    if (b == 0 && t == 0) row_ptr[N_NODES] = N_EDGES;
    __syncthreads();
    for (int i = t; i < n; i += PB_T) {
        uint2 ed = tb[i];
        int p = atomicAdd(&scur[ed.x >> 18], 1);
        edges[p] = make_uint2(ed.x & 0x3FFFFu, ed.y);
    }
}

// ---------------------------------------------------------------------------
// SpMM helpers
// ---------------------------------------------------------------------------
__device__ __forceinline__ void fma4(float4& a, float w, float4 v) {
    a.x += w * v.x; a.y += w * v.y; a.z += w * v.z; a.w += w * v.w;
}
__device__ __forceinline__ void fma16(float4& a, float w, uint2 u) {
    float2 lo = __half22float2(*(const __half2*)&u.x);
    float2 hi = __half22float2(*(const __half2*)&u.y);
    a.x = fmaf(w, lo.x, a.x); a.y = fmaf(w, lo.y, a.y);
    a.z = fmaf(w, hi.x, a.z); a.w = fmaf(w, hi.y, a.w);
}

// ---------------------------------------------------------------------------
// fp16-gather CSR SpMM: one wave per row; lane = (g, dq). 16-lane group reads
// a full 128B fp16 row per gather. Output: exact fp32 + fp16 copy for next.
// ---------------------------------------------------------------------------
__global__ void __launch_bounds__(256)
spmm16_kernel(const int* __restrict__ row_ptr,
              const uint2* __restrict__ edges,
              const uint2* __restrict__ hin16,
              float* __restrict__ hout,
              uint2* __restrict__ hout16) {
    int wave = (blockIdx.x * blockDim.x + threadIdx.x) >> 6;
    int lane = threadIdx.x & 63;
    if (wave >= N_NODES) return;
    int g  = lane >> 4;
    int dq = lane & 15;
    int start = row_ptr[wave];
    int end   = row_ptr[wave + 1];
    float4 a0 = make_float4(0.f, 0.f, 0.f, 0.f);
    float4 a1 = a0, a2 = a0, a3 = a0;
    int e = start;
    for (; e + 16 <= end; e += 16) {
        uint2 e0 = edges[e + g];
        uint2 e1 = edges[e + 4 + g];
        uint2 e2 = edges[e + 8 + g];
        uint2 e3 = edges[e + 12 + g];
        uint2 v0 = hin16[(int)e0.x * 16 + dq];
        uint2 v1 = hin16[(int)e1.x * 16 + dq];
        uint2 v2 = hin16[(int)e2.x * 16 + dq];
        uint2 v3 = hin16[(int)e3.x * 16 + dq];
        fma16(a0, __uint_as_float(e0.y), v0);
        fma16(a1, __uint_as_float(e1.y), v1);
        fma16(a2, __uint_as_float(e2.y), v2);
        fma16(a3, __uint_as_float(e3.y), v3);
    }
    for (; e < end; e += 4) {
        int ei = e + g;
        uint2 ed = (ei < end) ? edges[ei] : make_uint2(0u, 0u);
        uint2 v = hin16[(int)ed.x * 16 + dq];
        fma16(a0, __uint_as_float(ed.y), v);
    }
    float4 s = make_float4((a0.x + a1.x) + (a2.x + a3.x),
                           (a0.y + a1.y) + (a2.y + a3.y),
                           (a0.z + a1.z) + (a2.z + a3.z),
                           (a0.w + a1.w) + (a2.w + a3.w));
    s.x += __shfl_xor(s.x, 16); s.y += __shfl_xor(s.y, 16);
    s.z += __shfl_xor(s.z, 16); s.w += __shfl_xor(s.w, 16);
    s.x += __shfl_xor(s.x, 32); s.y += __shfl_xor(s.y, 32);
    s.z += __shfl_xor(s.z, 32); s.w += __shfl_xor(s.w, 32);
    if (g == 0) {
        int o = wave * 16 + dq;
        ((float4*)hout)[o] = s;
        hout16[o] = pack_half4(s);
    }
}

__global__ void __launch_bounds__(256)
spmm16_fused_kernel(const int* __restrict__ row_ptr,
                    const uint2* __restrict__ edges,
                    const uint2* __restrict__ hin16,
                    const float* __restrict__ ego,
                    const float* __restrict__ h1,
                    const float* __restrict__ h2,
                    float* __restrict__ h3,
                    float* __restrict__ hsum) {
    int wave = (blockIdx.x * blockDim.x + threadIdx.x) >> 6;
    int lane = threadIdx.x & 63;
    if (wave >= N_NODES) return;
    int g  = lane >> 4;
    int dq = lane & 15;
    int start = row_ptr[wave];
    int end   = row_ptr[wave + 1];
    float4 a0 = make_float4(0.f, 0.f, 0.f, 0.f);
    float4 a1 = a0, a2 = a0, a3 = a0;
    int e = start;
    for (; e + 16 <= end; e += 16) {
        uint2 e0 = edges[e + g];
        uint2 e1 = edges[e + 4 + g];
        uint2 e2 = edges[e + 8 + g];
        uint2 e3 = edges[e + 12 + g];
        uint2 v0 = hin16[(int)e0.x * 16 + dq];
        uint2 v1 = hin16[(int)e1.x * 16 + dq];
        uint2 v2 = hin16[(int)e2.x * 16 + dq];
        uint2 v3 = hin16[(int)e3.x * 16 + dq];
        fma16(a0, __uint_as_float(e0.y), v0);
        fma16(a1, __uint_as_float(e1.y), v1);
        fma16(a2, __uint_as_float(e2.y), v2);
        fma16(a3, __uint_as_float(e3.y), v3);
    }
    for (; e < end; e += 4) {
        int ei = e + g;
        uint2 ed = (ei < end) ? edges[ei] : make_uint2(0u, 0u);
        uint2 v = hin16[(int)ed.x * 16 + dq];
        fma16(a0, __uint_as_float(ed.y), v);
    }
    float4 s = make_float4((a0.x + a1.x) + (a2.x + a3.x),
                           (a0.y + a1.y) + (a2.y + a3.y),
                           (a0.z + a1.z) + (a2.z + a3.z),
                           (a0.w + a1.w) + (a2.w + a3.w));
    s.x += __shfl_xor(s.x, 16); s.y += __shfl_xor(s.y, 16);
    s.z += __shfl_xor(s.z, 16); s.w += __shfl_xor(s.w, 16);
    s.x += __shfl_xor(s.x, 32); s.y += __shfl_xor(s.y, 32);
    s.z += __shfl_xor(s.z, 32); s.w += __shfl_xor(s.w, 32);
    if (g == 0) {
        int o = wave * 16 + dq;
        float4 E  = ((const float4*)ego)[o];
        float4 H1 = ((const float4*)h1)[o];
        float4 H2 = ((const float4*)h2)[o];
        ((float4*)h3)[o] = s;
        ((float4*)hsum)[o] = make_float4(E.x + H1.x + H2.x + s.x,
                                         E.y + H1.y + H2.y + s.y,
                                         E.z + H1.z + H2.z + s.z,
                                         E.w + H1.w + H2.w + s.w);
    }
}

// ---------------------------------------------------------------------------
// fp32-gather variants (tier-2: workspace too small for fp16 tables)
// ---------------------------------------------------------------------------
__global__ void __launch_bounds__(256)
spmm_csr_kernel(const int* __restrict__ row_ptr,
                const uint2* __restrict__ edges,
                const float* __restrict__ hin,
                float* __restrict__ hout) {
    int wave = (blockIdx.x * blockDim.x + threadIdx.x) >> 6;
    int lane = threadIdx.x & 63;
    if (wave >= N_NODES) return;
    int g  = lane >> 4;
    int dq = lane & 15;
    const float4* __restrict__ hin4 = (const float4*)hin;
    int start = row_ptr[wave];
    int end   = row_ptr[wave + 1];
    float4 a0 = make_float4(0.f, 0.f, 0.f, 0.f);
    float4 a1 = a0, a2 = a0, a3 = a0;
    int e = start;
    for (; e + 16 <= end; e += 16) {
        uint2 e0 = edges[e + g];
        uint2 e1 = edges[e + 4 + g];
        uint2 e2 = edges[e + 8 + g];
        uint2 e3 = edges[e + 12 + g];
        float4 v0 = hin4[(int)e0.x * 16 + dq];
        float4 v1 = hin4[(int)e1.x * 16 + dq];
        float4 v2 = hin4[(int)e2.x * 16 + dq];
        float4 v3 = hin4[(int)e3.x * 16 + dq];
        fma4(a0, __uint_as_float(e0.y), v0);
        fma4(a1, __uint_as_float(e1.y), v1);
        fma4(a2, __uint_as_float(e2.y), v2);
        fma4(a3, __uint_as_float(e3.y), v3);
    }
    for (; e < end; e += 4) {
        int ei = e + g;
        uint2 ed = (ei < end) ? edges[ei] : make_uint2(0u, 0u);
        float4 v = hin4[(int)ed.x * 16 + dq];
        fma4(a0, __uint_as_float(ed.y), v);
    }
    float4 s = make_float4((a0.x + a1.x) + (a2.x + a3.x),
                           (a0.y + a1.y) + (a2.y + a3.y),
                           (a0.z + a1.z) + (a2.z + a3.z),
                           (a0.w + a1.w) + (a2.w + a3.w));
    s.x += __shfl_xor(s.x, 16); s.y += __shfl_xor(s.y, 16);
    s.z += __shfl_xor(s.z, 16); s.w += __shfl_xor(s.w, 16);
    s.x += __shfl_xor(s.x, 32); s.y += __shfl_xor(s.y, 32);
    s.z += __shfl_xor(s.z, 32); s.w += __shfl_xor(s.w, 32);
    if (g == 0) ((float4*)hout)[wave * 16 + dq] = s;
}

__global__ void __launch_bounds__(256)
spmm_csr_fused_kernel(const int* __restrict__ row_ptr,
                      const uint2* __restrict__ edges,
                      const float* __restrict__ h2,
                      const float* __restrict__ ego,
                      const float* __restrict__ h1,
                      float* __restrict__ h3,
                      float* __restrict__ hsum) {
    int wave = (blockIdx.x * blockDim.x + threadIdx.x) >> 6;
    int lane = threadIdx.x & 63;
    if (wave >= N_NODES) return;
    int g  = lane >> 4;
    int dq = lane & 15;
    const float4* __restrict__ h24 = (const float4*)h2;
    int start = row_ptr[wave];
    int end   = row_ptr[wave + 1];
    float4 a0 = make_float4(0.f, 0.f, 0.f, 0.f);
    float4 a1 = a0, a2 = a0, a3 = a0;
    int e = start;
    for (; e + 16 <= end; e += 16) {
        uint2 e0 = edges[e + g];
        uint2 e1 = edges[e + 4 + g];
        uint2 e2 = edges[e + 8 + g];
        uint2 e3 = edges[e + 12 + g];
        float4 v0 = h24[(int)e0.x * 16 + dq];
        float4 v1 = h24[(int)e1.x * 16 + dq];
        float4 v2 = h24[(int)e2.x * 16 + dq];
        float4 v3 = h24[(int)e3.x * 16 + dq];
        fma4(a0, __uint_as_float(e0.y), v0);
        fma4(a1, __uint_as_float(e1.y), v1);
        fma4(a2, __uint_as_float(e2.y), v2);
        fma4(a3, __uint_as_float(e3.y), v3);
    }
    for (; e < end; e += 4) {
        int ei = e + g;
        uint2 ed = (ei < end) ? edges[ei] : make_uint2(0u, 0u);
        float4 v = h24[(int)ed.x * 16 + dq];
        fma4(a0, __uint_as_float(ed.y), v);
    }
    float4 s = make_float4((a0.x + a1.x) + (a2.x + a3.x),
                           (a0.y + a1.y) + (a2.y + a3.y),
                           (a0.z + a1.z) + (a2.z + a3.z),
                           (a0.w + a1.w) + (a2.w + a3.w));
    s.x += __shfl_xor(s.x, 16); s.y += __shfl_xor(s.y, 16);
    s.z += __shfl_xor(s.z, 16); s.w += __shfl_xor(s.w, 16);
    s.x += __shfl_xor(s.x, 32); s.y += __shfl_xor(s.y, 32);
    s.z += __shfl_xor(s.z, 32); s.w += __shfl_xor(s.w, 32);
    if (g == 0) {
        int o = wave * 16 + dq;
        float4 E  = ((const float4*)ego)[o];
        float4 H1 = ((const float4*)h1)[o];
        float4 H2 = ((const float4*)h2)[o];
        ((float4*)h3)[o] = s;
        ((float4*)hsum)[o] = make_float4(E.x + H1.x + H2.x + s.x,
                                         E.y + H1.y + H2.y + s.y,
                                         E.z + H1.z + H2.z + s.z,
                                         E.w + H1.w + H2.w + s.w);
    }
}

// ---------------------------------------------------------------------------
// tier-3 fallback (tiny workspace): fp32 atomics
// ---------------------------------------------------------------------------
__global__ void spmm_atomic_kernel(const int* __restrict__ rows,
                                   const int* __restrict__ cols,
                                   const float* __restrict__ vals,
                                   const float* __restrict__ hin,
                                   float* __restrict__ hout) {
    int e = blockIdx.x * 4 + (threadIdx.x >> 6);
    int d = threadIdx.x & 63;
    if (e < N_EDGES) {
        atomicAdd(&hout[rows[e] * DIM + d], vals[e] * hin[cols[e] * DIM + d]);
    }
}

__global__ void zero_f_kernel(float* __restrict__ p, long long n) {
    long long i = (long long)blockIdx.x * blockDim.x + threadIdx.x;
    if (i < n) p[i] = 0.f;
}

__global__ void concat_kernel(const float4* __restrict__ user,
                              const float4* __restrict__ item,
                              float4* __restrict__ ego) {
    int i = blockIdx.x * blockDim.x + threadIdx.x;
    const int userF4 = N_USERS * DIM / 4;
    const int totF4  = (int)(NF / 4);
    if (i < userF4)      ego[i] = user[i];
    else if (i < totF4)  ego[i] = item[i - userF4];
}

__global__ void sum_kernel(const float4* __restrict__ a,
                           const float4* __restrict__ b,
                           const float4* __restrict__ c,
                           const float4* __restrict__ d,
                           float4* __restrict__ out) {
    int i = blockIdx.x * blockDim.x + threadIdx.x;
    if (i < (int)(NF / 4)) {
        float4 x = a[i], y = b[i], z = c[i], w = d[i];
        out[i] = make_float4(x.x + y.x + z.x + w.x,
                             x.y + y.y + z.y + w.y,
                             x.z + y.z + z.z + w.z,
                             x.w + y.w + z.w + w.w);
    }
}

extern "C" void kernel_launch(void* const* d_in, const int* in_sizes, int n_in,
                              void* d_out, int out_size, void* d_ws, size_t ws_size,
                              hipStream_t stream) {
    const float* user = (const float*)d_in[0];
    const float* item = (const float*)d_in[1];
    const float* vals = (const float*)d_in[2];
    const int*   rows = (const int*)d_in[3];
    const int*   cols = (const int*)d_in[4];

    float* out  = (float*)d_out;
    float* hsum = out;
    float* ego  = out + NF;
    float* h1   = out + 2 * NF;
    float* h2   = out + 3 * NF;
    float* h3   = out + 4 * NF;

    const int totF4 = (int)(NF / 4);

    const size_t edgesB = (size_t)N_EDGES * 8;
    const size_t h16B   = (size_t)N_NODES * DIM * 2;              // 19,200,128
    const size_t intsB  = ((size_t)NCHUNK * NCB + (size_t)N_NODES + 2
                           + NCB + 16) * 4;
    const size_t need32 = edgesB + intsB;
    const size_t need16 = edgesB + 2 * h16B + intsB;

    if (ws_size >= need32) {
        uint2* edges = (uint2*)d_ws;
        char*  p     = (char*)(edges + N_EDGES);
        uint2* hA    = nullptr;
        uint2* hB    = nullptr;
        bool   f16   = (ws_size >= need16);
        if (f16) {
            hA = (uint2*)p;  p += h16B;
            hB = (uint2*)p;  p += h16B;
        }
        int* cnt     = (int*)p;
        int* row_ptr = cnt + (size_t)NCHUNK * NCB;
        int* stored  = row_ptr + (N_NODES + 2);
        // tmp staging lives in the (still-dead) h1 output region
        uint2* tmp   = (uint2*)h1;

        fused_count_concat_kernel<<<NCHUNK + CONCAT_BLK, BINA_T, 0, stream>>>(
            rows, cnt, (const float4*)user, (const float4*)item,
            (float4*)ego, hA);
        binA_scan_kernel<<<NCB, BINA_T, 0, stream>>>(cnt, stored);
        binA_write_kernel<<<NCHUNK, BINA_T, 0, stream>>>(
            rows, cols, vals, cnt, stored, tmp);
        passB_kernel<<<NCB, PB_T, 0, stream>>>(stored, tmp, edges, row_ptr);

        const int spmmBlocks = (N_NODES * 64 + 255) / 256;  // 1 wave per row
        if (f16) {
            spmm16_kernel<<<spmmBlocks, 256, 0, stream>>>(row_ptr, edges, hA, h1, hB);
            spmm16_kernel<<<spmmBlocks, 256, 0, stream>>>(row_ptr, edges, hB, h2, hA);
            spmm16_fused_kernel<<<spmmBlocks, 256, 0, stream>>>(
                row_ptr, edges, hA, ego, h1, h2, h3, hsum);
        } else {
            spmm_csr_kernel<<<spmmBlocks, 256, 0, stream>>>(row_ptr, edges, ego, h1);
            spmm_csr_kernel<<<spmmBlocks, 256, 0, stream>>>(row_ptr, edges, h1,  h2);
            spmm_csr_fused_kernel<<<spmmBlocks, 256, 0, stream>>>(
                row_ptr, edges, h2, ego, h1, h3, hsum);
        }
    } else {
        concat_kernel<<<(totF4 + 255) / 256, 256, 0, stream>>>(
            (const float4*)user, (const float4*)item, (float4*)ego);
        const long long nz = 3 * NF;
        zero_f_kernel<<<(int)((nz + 255) / 256), 256, 0, stream>>>(h1, nz);
        const int ablocks = (N_EDGES + 3) / 4;
        spmm_atomic_kernel<<<ablocks, 256, 0, stream>>>(rows, cols, vals, ego, h1);
        spmm_atomic_kernel<<<ablocks, 256, 0, stream>>>(rows, cols, vals, h1,  h2);
        spmm_atomic_kernel<<<ablocks, 256, 0, stream>>>(rows, cols, vals, h2,  h3);
        sum_kernel<<<(totF4 + 255) / 256, 256, 0, stream>>>(
            (const float4*)ego, (const float4*)h1, (const float4*)h2, (const float4*)h3,
            (float4*)hsum);
    }
}